// Round 4
// baseline (301.383 us; speedup 1.0000x reference)
//
#include <hip/hip_runtime.h>
#include <math.h>

#define B_ 2
#define L_ 5000
#define E_ 20
#define H_ 5
#define FF_ 120
#define DEC_ 40
#define K_ 50
#define PAD_ 25
#define SCALE 0.22360679774997896f  // 1/sqrt(E)

#define NM 35                     // symmetric monomials deg<=3 in 4 vars
#define MST2 180                  // per-(b,h): 5 c-slots x 36 (35 used + pad)
#define LSTRIDE 1824              // per-layer M stride (floats)

// ---- persistent-kernel geometry ----
#define BLK_ 512                  // 64 positions x 8 parts; part = tid>>6 wave-uniform
#define NPOS 64
#define TPB_ 79                   // ceil(L/64) tiles per batch
#define GRID_ (B_ * TPB_)         // 158 blocks <= 256 CUs -> all co-resident

typedef float v2f __attribute__((ext_vector_type(2)));
__device__ __forceinline__ v2f vsplat(float x) { v2f r; r.x = x; r.y = x; return r; }

// monomial index tables; slot 4 is the constant-1 slot.
__constant__ int TD[NM] = {4, 0,1,2,3, 0,0,0,0,1,1,1,2,2,3,
                           0,0,0,0,0,0,0,0,0,0,1,1,1,1,1,1,2,2,2,3};
__constant__ int TE[NM] = {4, 4,4,4,4, 0,1,2,3,1,2,3,2,3,3,
                           0,0,0,0,1,1,1,2,2,3,1,1,1,2,2,3,2,2,3,3};
__constant__ int TF[NM] = {4, 4,4,4,4, 4,4,4,4,4,4,4,4,4,4,
                           0,1,2,3,1,2,3,2,3,3,1,2,3,2,3,3,2,3,3,3};

__device__ __forceinline__ void mono36(const float x[4], float m[36]) {
  int idx = 0;
  m[idx++] = 1.f;
#pragma unroll
  for (int d = 0; d < 4; d++) m[idx++] = x[d];
#pragma unroll
  for (int d = 0; d < 4; d++)
#pragma unroll
    for (int e = d; e < 4; e++) m[idx++] = x[d] * x[e];
#pragma unroll
  for (int d = 0; d < 4; d++)
#pragma unroll
    for (int e = d; e < 4; e++)
#pragma unroll
      for (int f = e; f < 4; f++) m[idx++] = x[d] * x[e] * x[f];
  m[35] = 0.f;
}

__device__ __forceinline__ void qcoef(float* mq) {
  const float S = 1.f / 6.f;
  mq[5]  *= 0.5f; mq[9]  *= 0.5f; mq[12] *= 0.5f; mq[14] *= 0.5f;
  mq[15] *= S;    mq[25] *= S;    mq[31] *= S;    mq[34] *= S;
  mq[16] *= 0.5f; mq[17] *= 0.5f; mq[18] *= 0.5f; mq[19] *= 0.5f;
  mq[22] *= 0.5f; mq[24] *= 0.5f; mq[26] *= 0.5f; mq[27] *= 0.5f;
  mq[28] *= 0.5f; mq[30] *= 0.5f; mq[32] *= 0.5f; mq[33] *= 0.5f;
}

// DOT macros work on generic pointers (LDS here -> ds_read_b128)
#define DOT20G(res, W, row, vec)                                     \
  {                                                                  \
    const float4* Wr = (const float4*)((W) + (row) * 20);            \
    float c0 = 0.f, c1 = 0.f, c2 = 0.f, c3 = 0.f;                    \
    _Pragma("unroll") for (int g5 = 0; g5 < 5; g5++) {               \
      float4 w4 = Wr[g5];                                            \
      c0 += w4.x * vec[g5 * 4 + 0];                                  \
      c1 += w4.y * vec[g5 * 4 + 1];                                  \
      c2 += w4.z * vec[g5 * 4 + 2];                                  \
      c3 += w4.w * vec[g5 * 4 + 3];                                  \
    }                                                                \
    res += (c0 + c1) + (c2 + c3);                                    \
  }

#define DOT40G(res, W, row, vec)                                     \
  {                                                                  \
    const float4* Wr = (const float4*)((W) + (row) * 40);            \
    float c0 = 0.f, c1 = 0.f, c2 = 0.f, c3 = 0.f;                    \
    _Pragma("unroll") for (int g5 = 0; g5 < 10; g5++) {              \
      float4 w4 = Wr[g5];                                            \
      c0 += w4.x * vec[g5 * 4 + 0];                                  \
      c1 += w4.y * vec[g5 * 4 + 1];                                  \
      c2 += w4.z * vec[g5 * 4 + 2];                                  \
      c3 += w4.w * vec[g5 * 4 + 3];                                  \
    }                                                                \
    res += (c0 + c1) + (c2 + c3);                                    \
  }

// LDS weight-buffer layout (floats)
enum { OWQ = 0, OWC = 16, OBC = 416, OLNAG = 436, OLNAB = 456, OW1 = 476,
       OB1 = 2876, OW2T = 2996, OB2 = 5396, OLNBG = 5416, OLNBB = 5436,
       WTOT = 5456,
       // decoder overlay (last phase only)
       OF1 = 0, OF1B = 800, OF2 = 840, OF2B = 2440, OF3 = 2480, OF3B = 3280,
       OF4 = 3300, OF4B = 3320 };

// Total LDS: u1 25.9KB + u2 21.8KB + stv2 5.4KB = 53.1KB < 64KB
struct SMEM {
  union {
    struct {
      float4 so4[NPOS][7];    // [p][head], padded
      float stv[NPOS * E_];   // [p][20] Wc hand-off
      float sh[NPOS * E_];    // [p][20] persistent current-h mirror
      float sM[H_ * MST2];    // this fb's staged M (900 f)
    } a;
    float dscratch[NPOS * 101];  // decoder scratch (6464 f), last phase only
  } u1;
  union {
    float w[WTOT];            // staged per-layer weights (or decoder weights)
    float kk[H_ * 10 * 66];   // moment staging [head][slot][pos], pad 66
  } u2;
  float stv2[NPOS * 21];      // FFN ds_add accumulator, stride 21 (bank-spread)
};

// ---------------------------------------------------------------------------
// Per-fb grid barrier (79 blocks each; the two batches are independent
// pipelines). RELAXED polling (no per-poll invalidate), one ACQUIRE on exit.
// cnt self-resets, gen monotonic -> replay/graph safe.
// ---------------------------------------------------------------------------
__device__ unsigned g_cnt[2] = {0, 0};
__device__ unsigned g_gen[2] = {0, 0};

__device__ __forceinline__ void grid_barrier(int fb) {
  __syncthreads();
  if (threadIdx.x == 0) {
    unsigned g = __hip_atomic_load(&g_gen[fb], __ATOMIC_RELAXED,
                                   __HIP_MEMORY_SCOPE_AGENT);
    unsigned arr = __hip_atomic_fetch_add(&g_cnt[fb], 1u, __ATOMIC_RELEASE,
                                          __HIP_MEMORY_SCOPE_AGENT);
    if (arr == TPB_ - 1) {
      __hip_atomic_store(&g_cnt[fb], 0u, __ATOMIC_RELAXED,
                         __HIP_MEMORY_SCOPE_AGENT);
      __hip_atomic_fetch_add(&g_gen[fb], 1u, __ATOMIC_RELEASE,
                             __HIP_MEMORY_SCOPE_AGENT);
    } else {
      while (__hip_atomic_load(&g_gen[fb], __ATOMIC_RELAXED,
                               __HIP_MEMORY_SCOPE_AGENT) == g) {
        __builtin_amdgcn_s_sleep(8);
      }
    }
    (void)__hip_atomic_load(&g_gen[fb], __ATOMIC_ACQUIRE,
                            __HIP_MEMORY_SCOPE_AGENT);
  }
  __syncthreads();
}

// ---------------------------------------------------------------------------
// Stage layer weights + this fb's M slice into LDS. Parallel coalesced
// float4 rounds; callers __syncthreads() after.
// ---------------------------------------------------------------------------
__device__ __forceinline__ void stage_layer(
    int tid, int fb, int layer,
    const float* __restrict__ Wq, const float* __restrict__ Wc,
    const float* __restrict__ bc, const float* __restrict__ lnAg,
    const float* __restrict__ lnAb, const float* __restrict__ W1,
    const float* __restrict__ b1, const float* __restrict__ W2,
    const float* __restrict__ b2, const float* __restrict__ lnBg,
    const float* __restrict__ lnBb, const float* __restrict__ Mall,
    SMEM* S) {
  float* w = S->u2.w;
  const float* WcL = Wc + layer * 400;
  const float* W1L = W1 + layer * 2400;
  const float* W2L = W2 + layer * 2400;
  const float* ML  = Mall + layer * LSTRIDE + fb * (H_ * MST2);
  for (int i = tid; i < 100; i += BLK_)
    ((float4*)(w + OWC))[i] = ((const float4*)WcL)[i];
  for (int i = tid; i < 600; i += BLK_)
    ((float4*)(w + OW1))[i] = ((const float4*)W1L)[i];
  for (int i = tid; i < 225; i += BLK_)
    ((float4*)S->u1.a.sM)[i] = ((const float4*)ML)[i];
  for (int i = tid; i < 2400; i += BLK_) {
    int e = i / FF_, j = i % FF_;
    w[OW2T + j * E_ + e] = W2L[i];
  }
  if (tid < 16) w[OWQ + tid] = Wq[layer * 16 + tid];
  else if (tid < 36)  w[OBC + tid - 16]    = bc[layer * 20 + tid - 16];
  else if (tid < 56)  w[OLNAG + tid - 36]  = lnAg[layer * 20 + tid - 36];
  else if (tid < 76)  w[OLNAB + tid - 56]  = lnAb[layer * 20 + tid - 56];
  else if (tid < 196) w[OB1 + tid - 76]    = b1[layer * 120 + tid - 76];
  else if (tid < 216) w[OB2 + tid - 196]   = b2[layer * 20 + tid - 196];
  else if (tid < 236) w[OLNBG + tid - 216] = lnBg[layer * 20 + tid - 216];
  else if (tid < 256) w[OLNBB + tid - 236] = lnBb[layer * 20 + tid - 236];
}

// ---------------------------------------------------------------------------
// In-block moment production (this block's 64 keys -> atomicAdd into Mdst).
// Uses u2.kk (overlays the weight buffer -- re-staged next phase anyway).
// ---------------------------------------------------------------------------
__device__ __forceinline__ void produce_M(
    int p, int part, int fb, bool act,
    const float* __restrict__ WkL, const float* __restrict__ WvL,
    float* __restrict__ Mdst, SMEM* S) {
  __syncthreads();  // prior readers of u2.w / writers of sh done
  float* kk = S->u2.kk;
  if (part < H_) {
    float4 s4 = *(const float4*)(S->u1.a.sh + p * E_ + part * 4);
    float vm = act ? 1.f : 0.f;
    float* base = kk + part * 660 + p;
#pragma unroll
    for (int d = 0; d < 4; d++)
      base[d * 66] = WkL[d * 4 + 0] * s4.x + WkL[d * 4 + 1] * s4.y +
                     WkL[d * 4 + 2] * s4.z + WkL[d * 4 + 3] * s4.w;
    base[4 * 66] = 1.f;
#pragma unroll
    for (int d = 0; d < 4; d++)
      base[(5 + d) * 66] = (WvL[d * 4 + 0] * s4.x + WvL[d * 4 + 1] * s4.y +
                            WvL[d * 4 + 2] * s4.z + WvL[d * 4 + 3] * s4.w) * vm;
    base[9 * 66] = vm;
  }
  __syncthreads();
  if (part < H_) {
    const float* kb = kk + part * 660;
#pragma unroll
    for (int r = 0; r < 3; r++) {
      int mc = p + r * 64;
      if (mc < NM * 5) {
        int m = mc / 5, c = mc - m * 5;
        int sd = TD[m] * 66, se = TE[m] * 66, sf = TF[m] * 66,
            sv = (5 + c) * 66;
        v2f acc = vsplat(0.f);
#pragma unroll 8
        for (int j = 0; j < NPOS; j += 2) {
          v2f a  = *(const v2f*)(kb + sd + j);
          v2f bq = *(const v2f*)(kb + se + j);
          v2f cq = *(const v2f*)(kb + sf + j);
          v2f vv = *(const v2f*)(kb + sv + j);
          acc += a * bq * cq * vv;
        }
        atomicAdd(&Mdst[(fb * H_ + part) * MST2 + c * 36 + m], acc.x + acc.y);
      }
    }
  }
}

// ---------------------------------------------------------------------------
// Fused layer phase -- ALL reads from LDS (w, sM, sh); h lives in registers.
// ---------------------------------------------------------------------------
__device__ __forceinline__ void fused_phase(
    int tid, int p, int part, float* hv, SMEM* S) {
  const float* w = S->u2.w;

  // ---- A: attention eval, head = part; parts 5-7 zero stv2 ----
  if (part < H_) {
    float4 qsrc = *(const float4*)(S->u1.a.sh + p * E_ + part * 4);
    float q[4];
#pragma unroll
    for (int d = 0; d < 4; d++) {
      q[d] = (w[OWQ + d * 4 + 0] * qsrc.x + w[OWQ + d * 4 + 1] * qsrc.y +
              w[OWQ + d * 4 + 2] * qsrc.z + w[OWQ + d * 4 + 3] * qsrc.w) *
             SCALE;
    }
    float mq[36];
    mono36(q, mq);
    qcoef(mq);
    const float* Mb = S->u1.a.sM + part * MST2;
    float oc[5];
#pragma unroll
    for (int c = 0; c < 5; c++) {
      const float4* Mr = (const float4*)(Mb + c * 36);
      float a0 = 0.f, a1 = 0.f, a2 = 0.f, a3 = 0.f;
#pragma unroll
      for (int g = 0; g < 9; g++) {
        float4 w4 = Mr[g];
        a0 += w4.x * mq[g * 4 + 0];
        a1 += w4.y * mq[g * 4 + 1];
        a2 += w4.z * mq[g * 4 + 2];
        a3 += w4.w * mq[g * 4 + 3];
      }
      oc[c] = (a0 + a1) + (a2 + a3);
    }
    float inv = 1.f / oc[4];
    S->u1.a.so4[p][part] =
        make_float4(oc[0] * inv, oc[1] * inv, oc[2] * inv, oc[3] * inv);
  } else {
    // zero the FFN accumulator for this position (parts 5/6/7 split 7/7/6)
    int e0 = (part - 5) * 7;
    int e1 = (part == 7) ? E_ : e0 + 7;
    for (int e = e0; e < e1; e++) S->stv2[p * 21 + e] = 0.f;
  }
  __syncthreads();

  // ---- B: Wc rows per part + bias -> stv ----
  float o[E_];
#pragma unroll
  for (int hh = 0; hh < H_; hh++) {
    float4 o4 = S->u1.a.so4[p][hh];
    o[hh * 4 + 0] = o4.x; o[hh * 4 + 1] = o4.y;
    o[hh * 4 + 2] = o4.z; o[hh * 4 + 3] = o4.w;
  }
  int r0 = (part < 4) ? part * 3 : 12 + (part - 4) * 2;
  int nr = (part < 4) ? 3 : 2;
  for (int r = 0; r < nr; r++) {
    int row = r0 + r;
    float acc = w[OBC + row];
    DOT20G(acc, w + OWC, row, o);
    S->u1.a.stv[p * E_ + row] = acc;
  }
  __syncthreads();

  // ---- C: add residual (hv regs), LN_A ----
  float tv[E_];
#pragma unroll
  for (int e4 = 0; e4 < 5; e4++) {
    float4 t4 = *(const float4*)(S->u1.a.stv + p * E_ + e4 * 4);
    tv[e4 * 4 + 0] = t4.x + hv[e4 * 4 + 0];
    tv[e4 * 4 + 1] = t4.y + hv[e4 * 4 + 1];
    tv[e4 * 4 + 2] = t4.z + hv[e4 * 4 + 2];
    tv[e4 * 4 + 3] = t4.w + hv[e4 * 4 + 3];
  }
  float mu = 0.f;
#pragma unroll
  for (int e = 0; e < E_; e++) mu += tv[e];
  mu *= (1.f / E_);
  float var = 0.f;
#pragma unroll
  for (int e = 0; e < E_; e++) { float d = tv[e] - mu; var += d * d; }
  var *= (1.f / E_);
  float rs = rsqrtf(var + 1e-5f);
  float h1[E_];
#pragma unroll
  for (int e = 0; e < E_; e++)
    h1[e] = (tv[e] - mu) * rs * w[OLNAG + e] + w[OLNAB + e];

  // ---- D: FFN, 15 rows per part; partials via LDS float atomics ----
  float g2p[E_];
#pragma unroll
  for (int e = 0; e < E_; e++) g2p[e] = 0.f;
  int jf0 = part * (FF_ / 8);
#pragma unroll
  for (int jj = 0; jj < FF_ / 8; jj++) {
    int j = jf0 + jj;
    float f = w[OB1 + j];
    DOT20G(f, w + OW1, j, h1);
    f = fmaxf(f, 0.f);
    const float4* Wr = (const float4*)(w + OW2T + j * 20);
#pragma unroll
    for (int g = 0; g < 5; g++) {
      float4 w4 = Wr[g];
      g2p[g * 4 + 0] += w4.x * f;
      g2p[g * 4 + 1] += w4.y * f;
      g2p[g * 4 + 2] += w4.z * f;
      g2p[g * 4 + 3] += w4.w * f;
    }
  }
#pragma unroll
  for (int e = 0; e < E_; e++) atomicAdd(&S->stv2[p * 21 + e], g2p[e]);
  __syncthreads();

  // ---- E: total + b2 + residual(h1), LN_B -> hv ----
  float g2[E_];
#pragma unroll
  for (int e = 0; e < E_; e++)
    g2[e] = w[OB2 + e] + h1[e] + S->stv2[p * 21 + e];
  float mu2 = 0.f;
#pragma unroll
  for (int e = 0; e < E_; e++) mu2 += g2[e];
  mu2 *= (1.f / E_);
  float var2 = 0.f;
#pragma unroll
  for (int e = 0; e < E_; e++) { float d = g2[e] - mu2; var2 += d * d; }
  var2 *= (1.f / E_);
  float rs2 = rsqrtf(var2 + 1e-5f);
#pragma unroll
  for (int e = 0; e < E_; e++)
    hv[e] = (g2[e] - mu2) * rs2 * w[OLNBG + e] + w[OLNBB + e];
}

// ---------------------------------------------------------------------------
// Persistent megakernel; 4 per-fb grid barriers:
// phase0(conv+PE+M0) | stage+fused0(+M1) | ... | stage+fused3+decoder
// ---------------------------------------------------------------------------
__global__ __launch_bounds__(BLK_) void megakernel(
    const float* __restrict__ x, const float* __restrict__ cw,
    const float* __restrict__ Wv, const float* __restrict__ Wk,
    const float* __restrict__ Wq, const float* __restrict__ Wc,
    const float* __restrict__ bc, const float* __restrict__ lnAg,
    const float* __restrict__ lnAb, const float* __restrict__ W1,
    const float* __restrict__ b1, const float* __restrict__ W2,
    const float* __restrict__ b2, const float* __restrict__ lnBg,
    const float* __restrict__ lnBb,
    const float* __restrict__ f1w, const float* __restrict__ f1b,
    const float* __restrict__ f2w, const float* __restrict__ f2b,
    const float* __restrict__ f3w, const float* __restrict__ f3b,
    const float* __restrict__ f4w, const float* __restrict__ f4b,
    float* __restrict__ out, float* __restrict__ Mall) {
  __shared__ SMEM S;
  const int tid = threadIdx.x;
  const int bid = blockIdx.x;
  const int p = tid & (NPOS - 1);
  const int part = tid >> 6;  // wave-uniform
  const int fb = bid / TPB_;
  const int l = (bid % TPB_) * NPOS + p;
  const bool act = l < L_;
  const int lc = act ? l : L_ - 1;
  const int pos = fb * L_ + lc;

  // ---- phase 0: conv embed + PE -> sh ----
  if (part < H_) {
    const float* xr = x + fb * L_;
#pragma unroll
    for (int d = 0; d < 4; d++) {
      int e = part * 4 + d;
      const float* wr = cw + e * K_;
      float a0 = 0.f, a1 = 0.f;
#pragma unroll
      for (int k = 0; k < K_; k += 2) {
        int i0 = lc + k - PAD_, i1 = i0 + 1;
        float x0 = (i0 >= 0 && i0 < L_) ? xr[i0] : 0.f;
        float x1 = (i1 >= 0 && i1 < L_) ? xr[i1] : 0.f;
        a0 += x0 * wr[k];
        a1 += x1 * wr[k + 1];
      }
      double expo =
          (e & 1) ? (double)(e + 1) / (double)E_ : (double)e / (double)E_;
      double factor = pow(10000.0, -expo);
      double arg = (double)lc * factor;
      float pe = (e & 1) ? (float)cos(arg) : (float)sin(arg);
      S.u1.a.sh[p * E_ + e] = (a0 + a1) + pe;
    }
  }
  produce_M(p, part, fb, act, Wk, Wv, Mall, &S);
  grid_barrier(fb);

  // residual h into registers
  float hv[E_];
#pragma unroll
  for (int g = 0; g < 5; g++) {
    float4 h4 = *(const float4*)(S.u1.a.sh + p * E_ + g * 4);
    hv[g * 4 + 0] = h4.x; hv[g * 4 + 1] = h4.y;
    hv[g * 4 + 2] = h4.z; hv[g * 4 + 3] = h4.w;
  }

  for (int layer = 0; layer < 4; layer++) {
    stage_layer(tid, fb, layer, Wq, Wc, bc, lnAg, lnAb, W1, b1, W2, b2,
                lnBg, lnBb, Mall, &S);
    __syncthreads();
    fused_phase(tid, p, part, hv, &S);

    if (layer < 3) {
      if (part == 0) {
#pragma unroll
        for (int g = 0; g < 5; g++)
          *(float4*)(S.u1.a.sh + p * E_ + g * 4) =
              make_float4(hv[g * 4], hv[g * 4 + 1], hv[g * 4 + 2],
                          hv[g * 4 + 3]);
      }
      produce_M(p, part, fb, act, Wk + (layer + 1) * 16,
                Wv + (layer + 1) * 16, Mall + (layer + 1) * LSTRIDE, &S);
      grid_barrier(fb);
    } else {
      // ---- decoder: restage f-weights over u2.w, scratch over u1 ----
      __syncthreads();  // E's LDS reads (w, stv2) complete
      float* w = S.u2.w;
      for (int i = tid; i < 200; i += BLK_)
        ((float4*)(w + OF1))[i] = ((const float4*)f1w)[i];
      for (int i = tid; i < 400; i += BLK_)
        ((float4*)(w + OF2))[i] = ((const float4*)f2w)[i];
      for (int i = tid; i < 200; i += BLK_)
        ((float4*)(w + OF3))[i] = ((const float4*)f3w)[i];
      if (tid < 20) w[OF4 + tid] = f4w[tid];
      else if (tid < 60)  w[OF1B + tid - 20]  = f1b[tid - 20];
      else if (tid < 100) w[OF2B + tid - 60]  = f2b[tid - 60];
      else if (tid < 120) w[OF3B + tid - 100] = f3b[tid - 100];
      else if (tid == 120) w[OF4B] = f4b[0];
      __syncthreads();

      float* dsc = S.u1.dscratch;
#pragma unroll
      for (int j = 0; j < DEC_ / 8; j++) {
        int jj = part * (DEC_ / 8) + j;
        float a = w[OF1B + jj];
        DOT20G(a, w + OF1, jj, hv);
        dsc[p * 101 + jj] = fmaxf(a, 0.f);
      }
      __syncthreads();
      float d1[DEC_];
#pragma unroll
      for (int k = 0; k < DEC_; k++) d1[k] = dsc[p * 101 + k];
#pragma unroll
      for (int j = 0; j < DEC_ / 8; j++) {
        int jj = part * (DEC_ / 8) + j;
        float a = w[OF2B + jj];
        DOT40G(a, w + OF2, jj, d1);
        dsc[p * 101 + 40 + jj] = fmaxf(a, 0.f);
      }
      __syncthreads();
      float d2[DEC_];
#pragma unroll
      for (int k = 0; k < DEC_; k++) d2[k] = dsc[p * 101 + 40 + k];
      if (part < 5) {
#pragma unroll
        for (int j = 0; j < 4; j++) {
          int ee = part * 4 + j;
          float a = w[OF3B + ee];
          DOT40G(a, w + OF3, ee, d2);
          dsc[p * 101 + 80 + ee] = fmaxf(a, 0.f);
        }
      }
      __syncthreads();
      if (act && part == 0) {
        float z = w[OF4B];
        const float* dv = dsc + p * 101 + 80;
        DOT20G(z, w + OF4, 0, dv);
        out[pos] = 1.f / (1.f + __expf(-z));
      }
    }
  }
}

// ---------------------------------------------------------------------------
extern "C" void kernel_launch(void* const* d_in, const int* in_sizes, int n_in,
                              void* d_out, int out_size, void* d_ws,
                              size_t ws_size, hipStream_t stream) {
  const float* x    = (const float*)d_in[0];
  const float* cw   = (const float*)d_in[1];
  const float* Wv   = (const float*)d_in[2];
  const float* Wk   = (const float*)d_in[3];
  const float* Wq   = (const float*)d_in[4];
  const float* Wc   = (const float*)d_in[5];
  const float* bc   = (const float*)d_in[6];
  const float* lnAg = (const float*)d_in[7];
  const float* lnAb = (const float*)d_in[8];
  const float* W1   = (const float*)d_in[9];
  const float* b1   = (const float*)d_in[10];
  const float* W2   = (const float*)d_in[11];
  const float* b2   = (const float*)d_in[12];
  const float* lnBg = (const float*)d_in[13];
  const float* lnBb = (const float*)d_in[14];
  const float* f1w  = (const float*)d_in[15];
  const float* f1b  = (const float*)d_in[16];
  const float* f2w  = (const float*)d_in[17];
  const float* f2b  = (const float*)d_in[18];
  const float* f3w  = (const float*)d_in[19];
  const float* f3b  = (const float*)d_in[20];
  const float* f4w  = (const float*)d_in[21];
  const float* f4b  = (const float*)d_in[22];
  float* out = (float*)d_out;

  float* Mall = (float*)d_ws;  // 4*LSTRIDE floats

  // zero M before the kernel (stream-ordered -> no zero-vs-atomic race)
  hipMemsetAsync(Mall, 0, 4 * LSTRIDE * sizeof(float), stream);

  megakernel<<<dim3(GRID_), dim3(BLK_), 0, stream>>>(
      x, cw, Wv, Wk, Wq, Wc, bc, lnAg, lnAb, W1, b1, W2, b2, lnBg, lnBb,
      f1w, f1b, f2w, f2b, f3w, f3b, f4w, f4b, out, Mall);
}